// Round 2
// baseline (743.123 us; speedup 1.0000x reference)
//
#include <hip/hip_runtime.h>
#include <math.h>

// Problem constants (from reference): B=32, S=512, F=4096.
#define BB 32
#define SS 512
#define FF 4096
#define F2 (FF / 2)   // features per float2 lane pair

// One thread per (b, f-pair). Serial loop over t (true data dependence
// through |state|). float2 loads -> 8 B/lane (BW sweet spot); float4 store.
// Key identity: state * exp(i*(angle(x)-angle(state))) == |state| * x/|x|,
// which removes all atan2/sincos from the inner loop.
__global__ __launch_bounds__(256) void spectral_ema_kernel(
    const float* __restrict__ fft_real,   // [B,S,F]
    const float* __restrict__ fft_imag,   // [B,S,F]
    const float* __restrict__ init_real,  // [B,F]
    const float* __restrict__ init_imag,  // [B,F]
    const float* __restrict__ rho_logit,  // [F]
    const float* __restrict__ theta_raw,  // [F]
    float* __restrict__ out)              // [B,F,2]
{
    const int id = blockIdx.x * blockDim.x + threadIdx.x;   // 0 .. B*F/2-1
    const int f2 = id & (F2 - 1);          // feature-pair index
    const int b  = id >> 11;               // id / F2

    // Per-feature decay params for the two features this thread owns.
    const float2 rl = *reinterpret_cast<const float2*>(rho_logit + 2 * f2);
    const float2 tr = *reinterpret_cast<const float2*>(theta_raw + 2 * f2);

    const float rho0 = 1.0f / (1.0f + expf(-rl.x));
    const float rho1 = 1.0f / (1.0f + expf(-rl.y));
    const float th0  = 3.14159265358979323846f * tanhf(tr.x);
    const float th1  = 3.14159265358979323846f * tanhf(tr.y);
    float s0, c0, s1, c1;
    __sincosf(th0, &s0, &c0);
    __sincosf(th1, &s1, &c1);
    const float ar0 = rho0 * c0, ai0 = rho0 * s0, om0 = 1.0f - rho0;
    const float ar1 = rho1 * c1, ai1 = rho1 * s1, om1 = 1.0f - rho1;

    const float2 ir = *reinterpret_cast<const float2*>(init_real + (size_t)b * FF + 2 * f2);
    const float2 ii = *reinterpret_cast<const float2*>(init_imag + (size_t)b * FF + 2 * f2);
    float sr0 = ir.x, sr1 = ir.y;
    float si0 = ii.x, si1 = ii.y;

    const float2* pr = reinterpret_cast<const float2*>(fft_real + (size_t)b * SS * FF) + f2;
    const float2* pi = reinterpret_cast<const float2*>(fft_imag + (size_t)b * SS * FF) + f2;

    #pragma unroll 8
    for (int t = 0; t < SS; ++t) {
        const float2 xr = pr[(size_t)t * F2];
        const float2 xi = pi[(size_t)t * F2];

        // ---- feature 0 ----
        {
            const float m2x = xr.x * xr.x + xi.x * xi.x;
            const float ms  = sqrtf(sr0 * sr0 + si0 * si0);
            float uxr, uxi;
            if (m2x > 0.0f) {
                const float inv = rsqrtf(m2x);
                uxr = xr.x * inv; uxi = xi.x * inv;
            } else { uxr = 1.0f; uxi = 0.0f; }   // angle(0)=0 -> phase 1+0i
            const float rr = ms * uxr, ri = ms * uxi;
            sr0 = ar0 * rr - ai0 * ri + om0 * xr.x;
            si0 = ar0 * ri + ai0 * rr + om0 * xi.x;
        }
        // ---- feature 1 ----
        {
            const float m2x = xr.y * xr.y + xi.y * xi.y;
            const float ms  = sqrtf(sr1 * sr1 + si1 * si1);
            float uxr, uxi;
            if (m2x > 0.0f) {
                const float inv = rsqrtf(m2x);
                uxr = xr.y * inv; uxi = xi.y * inv;
            } else { uxr = 1.0f; uxi = 0.0f; }
            const float rr = ms * uxr, ri = ms * uxi;
            sr1 = ar1 * rr - ai1 * ri + om1 * xr.y;
            si1 = ar1 * ri + ai1 * rr + om1 * xi.y;
        }
    }

    // out[b][f][0..1] for f = 2*f2, 2*f2+1 -> contiguous float4, 16B aligned.
    float4 o;
    o.x = sr0; o.y = si0; o.z = sr1; o.w = si1;
    *reinterpret_cast<float4*>(out + (size_t)b * FF * 2 + (size_t)4 * f2) = o;
}

extern "C" void kernel_launch(void* const* d_in, const int* in_sizes, int n_in,
                              void* d_out, int out_size, void* d_ws, size_t ws_size,
                              hipStream_t stream) {
    const float* fft_real  = (const float*)d_in[0];
    const float* fft_imag  = (const float*)d_in[1];
    const float* init_real = (const float*)d_in[2];
    const float* init_imag = (const float*)d_in[3];
    const float* rho_logit = (const float*)d_in[4];
    const float* theta_raw = (const float*)d_in[5];
    float* out = (float*)d_out;

    const int total = BB * F2;           // 65536 threads (one per feature pair)
    const int block = 256;
    const int grid  = total / block;     // 256 blocks

    spectral_ema_kernel<<<grid, block, 0, stream>>>(
        fft_real, fft_imag, init_real, init_imag, rho_logit, theta_raw, out);
}